// Round 10
// baseline (107.908 us; speedup 1.0000x reference)
//
#include <hip/hip_runtime.h>
#include <hip/hip_bf16.h>

#define B_ROWS 4096
#define DIM 256
#define NPAIR 6
#define PITCH 4160              // XT row pitch (elems): 4096+64 breaks pow2 L2 aliasing
#define KSPLIT 8
#define KCHUNK (B_ROWS / KSPLIT)   // 512 (fallback path)

typedef short bf16x8 __attribute__((ext_vector_type(8)));
typedef float f32x4 __attribute__((ext_vector_type(4)));

__device__ __forceinline__ const float* sel(const float* e0, const float* e1,
                                            const float* e2, const float* e3, int i) {
    return i == 0 ? e0 : (i == 1 ? e1 : (i == 2 ? e2 : e3));
}

// pair p -> (pi, pj): (0,1),(0,2),(0,3),(1,2),(1,3),(2,3)
__device__ __forceinline__ int pair_i(int p) { return p < 3 ? 0 : (p < 5 ? 1 : 2); }
__device__ __forceinline__ int pair_j(int p) { return p < 3 ? p + 1 : (p < 5 ? p - 1 : 3); }

__device__ __forceinline__ unsigned short f32_to_bf16_rne(float f) {
    unsigned int u = __float_as_uint(f);
    unsigned int r = (u + 0x7FFFu + ((u >> 16) & 1u)) >> 16;
    return (unsigned short)r;
}

// ============================ MFMA PATH ============================

// Kernel 1: transpose + convert + fused column sums.
// X[e] (4096x256 f32) -> XT[e] (256 rows x PITCH bf16); sums[e][c] += partials.
__global__ __launch_bounds__(256) void transpose_bf16_kernel(
        const float* __restrict__ e0, const float* __restrict__ e1,
        const float* __restrict__ e2, const float* __restrict__ e3,
        unsigned short* __restrict__ XT, float* __restrict__ sums) {
    int rt = blockIdx.x;   // 0..63  (row tile of X, 64 rows)
    int ct = blockIdx.y;   // 0..3   (col tile of X, 64 cols)
    int e  = blockIdx.z;   // 0..3
    const float* X = sel(e0, e1, e2, e3, e);
    unsigned short* XTe = XT + (size_t)e * DIM * PITCH;

    __shared__ float T[64][65];

    int t = threadIdx.x;
    int c4 = (t & 15) << 2;          // 0,4,...,60
    #pragma unroll
    for (int p = 0; p < 4; ++p) {
        int r = (t >> 4) + 16 * p;   // 0..63
        float4 v = *(const float4*)&X[(size_t)(rt * 64 + r) * DIM + ct * 64 + c4];
        T[c4 + 0][r] = v.x;
        T[c4 + 1][r] = v.y;
        T[c4 + 2][r] = v.z;
        T[c4 + 3][r] = v.w;
    }
    __syncthreads();

    #pragma unroll
    for (int p = 0; p < 2; ++p) {
        int id = 256 * p + t;        // 0..511
        int c = id >> 3;             // 0..63  (column of X within this tile)
        int roff = (id & 7) * 8;     // 0..56  (row offset within 64-row tile)
        bf16x8 outv;
        float s8 = 0.f;
        #pragma unroll
        for (int s = 0; s < 8; ++s) {
            float f = T[c][roff + s];
            outv[s] = (short)f32_to_bf16_rne(f);
            s8 += f;
        }
        *(bf16x8*)&XTe[(size_t)(ct * 64 + c) * PITCH + rt * 64 + roff] = outv;
        // the 8 threads covering column c are lane-consecutive -> segment reduce
        s8 += __shfl_down(s8, 4, 8);
        s8 += __shfl_down(s8, 2, 8);
        s8 += __shfl_down(s8, 1, 8);
        if ((id & 7) == 0) atomicAdd(&sums[e * DIM + ct * 64 + c], s8);
    }
}

// Kernel 2: fused MFMA gram (in-block split-K) + centered squared-sum reduce.
// One 512-thread block (8 waves) per (pair, 32x32 tile); wave w handles K-chunk
// [w*512, w*512+512); LDS tree-sum of partial tiles; one atomic per block.
__global__ __launch_bounds__(512) void gram_fused_kernel(
        const unsigned short* __restrict__ XT, const float* __restrict__ sums,
        float* __restrict__ acc_out) {
    int blk = blockIdx.x;            // 0..383
    int p = blk >> 6;                // 0..5
    int tile = blk & 63;             // 8x8 grid of 32x32 tiles
    int a0 = (tile >> 3) * 32;
    int b0 = (tile & 7) * 32;
    int pi = pair_i(p), pj = pair_j(p);
    const unsigned short* Xp = XT + (size_t)pi * DIM * PITCH;
    const unsigned short* Yp = XT + (size_t)pj * DIM * PITCH;

    int tid = threadIdx.x;
    int w = tid >> 6;                // wave 0..7 -> K-chunk
    int L = tid & 63;
    int mrow = L & 15;               // fragment row (m or n)
    int kq = (L >> 4) * 8;           // k sub-offset within 32
    int kbase = w * 512;

    const unsigned short* xa0 = Xp + (size_t)(a0 + mrow) * PITCH + kbase + kq;
    const unsigned short* xa1 = Xp + (size_t)(a0 + 16 + mrow) * PITCH + kbase + kq;
    const unsigned short* yb0 = Yp + (size_t)(b0 + mrow) * PITCH + kbase + kq;
    const unsigned short* yb1 = Yp + (size_t)(b0 + 16 + mrow) * PITCH + kbase + kq;

    f32x4 acc[2][2] = {};

    #pragma unroll 4
    for (int k0 = 0; k0 < 512; k0 += 32) {
        bf16x8 af0 = *(const bf16x8*)(xa0 + k0);
        bf16x8 af1 = *(const bf16x8*)(xa1 + k0);
        bf16x8 bf0 = *(const bf16x8*)(yb0 + k0);
        bf16x8 bf1 = *(const bf16x8*)(yb1 + k0);
        acc[0][0] = __builtin_amdgcn_mfma_f32_16x16x32_bf16(af0, bf0, acc[0][0], 0, 0, 0);
        acc[0][1] = __builtin_amdgcn_mfma_f32_16x16x32_bf16(af0, bf1, acc[0][1], 0, 0, 0);
        acc[1][0] = __builtin_amdgcn_mfma_f32_16x16x32_bf16(af1, bf0, acc[1][0], 0, 0, 0);
        acc[1][1] = __builtin_amdgcn_mfma_f32_16x16x32_bf16(af1, bf1, acc[1][1], 0, 0, 0);
    }

    // Stage partial 32x32 tiles to LDS (stride 33 keeps banks 2-way max = free).
    // C/D layout: col = lane&15, row = (lane>>4)*4 + reg   [measured m89/m91]
    __shared__ float red[8][32 * 33];
    #pragma unroll
    for (int ti = 0; ti < 2; ++ti)
        #pragma unroll
        for (int tj = 0; tj < 2; ++tj)
            #pragma unroll
            for (int r = 0; r < 4; ++r) {
                int m = ti * 16 + (L >> 4) * 4 + r;
                int n = tj * 16 + (L & 15);
                red[w][m * 33 + n] = acc[ti][tj][r];
            }
    __syncthreads();

    // 512 threads sum 8 partials for 2 positions each, center, square.
    const float inv_b = 1.0f / (float)B_ROWS;
    float local = 0.f;
    #pragma unroll
    for (int q = 0; q < 2; ++q) {
        int pos = tid + q * 512;     // 0..1023
        int m = pos >> 5, n = pos & 31;
        float s = 0.f;
        #pragma unroll
        for (int ww = 0; ww < 8; ++ww) s += red[ww][m * 33 + n];
        float v = s - sums[pi * DIM + a0 + m] * sums[pj * DIM + b0 + n] * inv_b;
        local = fmaf(v, v, local);
    }
    #pragma unroll
    for (int off = 32; off > 0; off >>= 1) local += __shfl_down(local, off, 64);
    __shared__ float wsum[8];
    if (L == 0) wsum[w] = local;
    __syncthreads();
    if (tid == 0) {
        float s = 0.f;
        #pragma unroll
        for (int ww = 0; ww < 8; ++ww) s += wsum[ww];
        atomicAdd(acc_out, s);
    }
}

// Kernel 3: scale and write the scalar output (float32)
__global__ void finalize_kernel(const float* __restrict__ acc, float* __restrict__ out) {
    if (threadIdx.x == 0) {
        const float scale = 0.1f / (6.0f * 4095.0f * 4095.0f);
        out[0] = acc[0] * scale;
    }
}

// ============================ FALLBACK (R3 passing fp32 path) ============================

__global__ void col_sums_kernel(const float* __restrict__ e0, const float* __restrict__ e1,
                                const float* __restrict__ e2, const float* __restrict__ e3,
                                float* __restrict__ sums) {
    int e = blockIdx.y;
    const float* X = sel(e0, e1, e2, e3, e);
    int c = threadIdx.x;
    int r0 = blockIdx.x * 128;
    float s = 0.f;
    #pragma unroll 4
    for (int r = r0; r < r0 + 128; ++r) s += X[r * DIM + c];
    atomicAdd(&sums[e * DIM + c], s);
}

__global__ __launch_bounds__(256) void gram_kernel(
        const float* __restrict__ e0, const float* __restrict__ e1,
        const float* __restrict__ e2, const float* __restrict__ e3,
        float* __restrict__ G) {
    int kc = blockIdx.x;
    int tile = blockIdx.y;
    int p = blockIdx.z;
    const float* X = sel(e0, e1, e2, e3, pair_i(p));
    const float* Y = sel(e0, e1, e2, e3, pair_j(p));
    int a0 = (tile >> 2) * 64;
    int b0 = (tile & 3) * 64;
    int k0 = kc * KCHUNK;
    __shared__ float As[16][64];
    __shared__ float Bs[16][64];
    int lid = threadIdx.x;
    int lr = lid >> 4;
    int lc = (lid & 15) << 2;
    int ty = lid >> 4;
    int tx = lid & 15;
    float acc[4][4] = {};
    for (int ks = 0; ks < KCHUNK; ks += 16) {
        int row = k0 + ks + lr;
        float4 av = *(const float4*)&X[row * DIM + a0 + lc];
        float4 bv = *(const float4*)&Y[row * DIM + b0 + lc];
        __syncthreads();
        *(float4*)&As[lr][lc] = av;
        *(float4*)&Bs[lr][lc] = bv;
        __syncthreads();
        #pragma unroll
        for (int k = 0; k < 16; ++k) {
            float a[4], b[4];
            *(float4*)a = *(const float4*)&As[k][ty * 4];
            *(float4*)b = *(const float4*)&Bs[k][tx * 4];
            #pragma unroll
            for (int i = 0; i < 4; ++i)
                #pragma unroll
                for (int j = 0; j < 4; ++j)
                    acc[i][j] = fmaf(a[i], b[j], acc[i][j]);
        }
    }
    float* Gp = G + p * (DIM * DIM);
    #pragma unroll
    for (int i = 0; i < 4; ++i)
        #pragma unroll
        for (int j = 0; j < 4; ++j)
            atomicAdd(&Gp[(a0 + ty * 4 + i) * DIM + (b0 + tx * 4 + j)], acc[i][j]);
}

__global__ void reduce_kernel(const float* __restrict__ G, const float* __restrict__ sums,
                              float* __restrict__ acc) {
    float local = 0.f;
    const int total = NPAIR * DIM * DIM;
    for (int idx = blockIdx.x * blockDim.x + threadIdx.x; idx < total;
         idx += gridDim.x * blockDim.x) {
        int p = idx >> 16;
        int ab = idx & 65535;
        int a = ab >> 8;
        int b = ab & 255;
        float v = G[idx] - sums[pair_i(p) * DIM + a] * sums[pair_j(p) * DIM + b] * (1.0f / (float)B_ROWS);
        local = fmaf(v, v, local);
    }
    #pragma unroll
    for (int off = 32; off > 0; off >>= 1) local += __shfl_down(local, off, 64);
    __shared__ float wsum[4];
    if ((threadIdx.x & 63) == 0) wsum[threadIdx.x >> 6] = local;
    __syncthreads();
    if (threadIdx.x == 0) {
        float s = wsum[0] + wsum[1] + wsum[2] + wsum[3];
        atomicAdd(acc, s);
    }
}

// ============================ LAUNCH ============================

extern "C" void kernel_launch(void* const* d_in, const int* in_sizes, int n_in,
                              void* d_out, int out_size, void* d_ws, size_t ws_size,
                              hipStream_t stream) {
    const float* e0 = (const float*)d_in[0];
    const float* e1 = (const float*)d_in[1];
    const float* e2 = (const float*)d_in[2];
    const float* e3 = (const float*)d_in[3];

    float* sums = (float*)d_ws;                            // 4*256 f32 = 4 KB
    float* acc  = (float*)((char*)d_ws + 4096);            // 1 f32
    // MFMA path scratch: XT bf16 at +8192, 4*256*PITCH*2 ≈ 8.1 MB
    size_t need = 8192 + (size_t)4 * DIM * PITCH * sizeof(unsigned short);

    if (ws_size >= need) {
        unsigned short* XT = (unsigned short*)((char*)d_ws + 8192);
        hipMemsetAsync(d_ws, 0, 8192, stream);   // sums + acc
        transpose_bf16_kernel<<<dim3(64, 4, 4), 256, 0, stream>>>(e0, e1, e2, e3, XT, sums);
        gram_fused_kernel<<<NPAIR * 64, 512, 0, stream>>>(XT, sums, acc);
        finalize_kernel<<<1, 64, 0, stream>>>(acc, (float*)d_out);
    } else {
        // fallback: fp32 vector path (passed in R3)
        float* G = (float*)((char*)d_ws + 8192);
        size_t zbytes = 8192 + (size_t)NPAIR * DIM * DIM * sizeof(float);
        hipMemsetAsync(d_ws, 0, zbytes, stream);
        col_sums_kernel<<<dim3(32, 4), 256, 0, stream>>>(e0, e1, e2, e3, sums);
        gram_kernel<<<dim3(KSPLIT, 16, NPAIR), 256, 0, stream>>>(e0, e1, e2, e3, G);
        reduce_kernel<<<384, 256, 0, stream>>>(G, sums, acc);
        finalize_kernel<<<1, 64, 0, stream>>>(acc, (float*)d_out);
    }
}

// Round 12
// 91.600 us; speedup vs baseline: 1.1780x; 1.1780x over previous
//
#include <hip/hip_runtime.h>
#include <hip/hip_bf16.h>

#define B_ROWS 4096
#define DIM 256
#define NPAIR 6
#define PITCH 4160              // XT row pitch (elems)
#define BK 256                  // K-chunk (elems) staged per iteration
#define APITCH 264              // LDS row pitch in shorts (256 + 8 pad = 528 B, 16B-aligned)
#define KSPLIT 8
#define KCHUNK (B_ROWS / KSPLIT)   // 512 (fallback path)

typedef short bf16x8 __attribute__((ext_vector_type(8)));
typedef float f32x4 __attribute__((ext_vector_type(4)));

__device__ __forceinline__ const float* sel(const float* e0, const float* e1,
                                            const float* e2, const float* e3, int i) {
    return i == 0 ? e0 : (i == 1 ? e1 : (i == 2 ? e2 : e3));
}

// pair p -> (pi, pj): (0,1),(0,2),(0,3),(1,2),(1,3),(2,3)
__device__ __forceinline__ int pair_i(int p) { return p < 3 ? 0 : (p < 5 ? 1 : 2); }
__device__ __forceinline__ int pair_j(int p) { return p < 3 ? p + 1 : (p < 5 ? p - 1 : 3); }

__device__ __forceinline__ unsigned short f32_to_bf16_rne(float f) {
    unsigned int u = __float_as_uint(f);
    unsigned int r = (u + 0x7FFFu + ((u >> 16) & 1u)) >> 16;
    return (unsigned short)r;
}

// ============================ MFMA PATH ============================

// Kernel 1: transpose + convert + fused column sums (unchanged from R10, passing).
__global__ __launch_bounds__(256) void transpose_bf16_kernel(
        const float* __restrict__ e0, const float* __restrict__ e1,
        const float* __restrict__ e2, const float* __restrict__ e3,
        unsigned short* __restrict__ XT, float* __restrict__ sums) {
    int rt = blockIdx.x;   // 0..63
    int ct = blockIdx.y;   // 0..3
    int e  = blockIdx.z;   // 0..3
    const float* X = sel(e0, e1, e2, e3, e);
    unsigned short* XTe = XT + (size_t)e * DIM * PITCH;

    __shared__ float T[64][65];

    int t = threadIdx.x;
    int c4 = (t & 15) << 2;
    #pragma unroll
    for (int p = 0; p < 4; ++p) {
        int r = (t >> 4) + 16 * p;
        float4 v = *(const float4*)&X[(size_t)(rt * 64 + r) * DIM + ct * 64 + c4];
        T[c4 + 0][r] = v.x;
        T[c4 + 1][r] = v.y;
        T[c4 + 2][r] = v.z;
        T[c4 + 3][r] = v.w;
    }
    __syncthreads();

    #pragma unroll
    for (int p = 0; p < 2; ++p) {
        int id = 256 * p + t;
        int c = id >> 3;
        int roff = (id & 7) * 8;
        bf16x8 outv;
        float s8 = 0.f;
        #pragma unroll
        for (int s = 0; s < 8; ++s) {
            float f = T[c][roff + s];
            outv[s] = (short)f32_to_bf16_rne(f);
            s8 += f;
        }
        *(bf16x8*)&XTe[(size_t)(ct * 64 + c) * PITCH + rt * 64 + roff] = outv;
        s8 += __shfl_down(s8, 4, 8);
        s8 += __shfl_down(s8, 2, 8);
        s8 += __shfl_down(s8, 1, 8);
        if ((id & 7) == 0) atomicAdd(&sums[e * DIM + ct * 64 + c], s8);
    }
}

// Kernel 2 (v3): LDS-staged MFMA gram. 384 blocks x 512 threads.
// Per BK=256 chunk: coalesced stage of A(32 rows)+B(32 rows), then 8 waves each
// consume a disjoint 32-k slice (4 ds_read_b128 + 4 MFMA). Register prefetch of
// the next chunk overlaps global latency with compute. Epilogue: LDS tree-sum
// of the 8 per-wave partial tiles, center, square, one atomic per block.
__global__ __launch_bounds__(512) void gram_v3_kernel(
        const unsigned short* __restrict__ XT, const float* __restrict__ sums,
        float* __restrict__ acc_out) {
    __shared__ __align__(16) unsigned short smem[2 * 32 * APITCH];  // 33792 B
    unsigned short* As = smem;
    unsigned short* Bs = smem + 32 * APITCH;
    float* red = (float*)smem;   // reused after K-loop

    int blk = blockIdx.x;            // 0..383
    int p = blk >> 6;
    int tile = blk & 63;
    int a0 = (tile >> 3) * 32;
    int b0 = (tile & 7) * 32;
    int pi = pair_i(p), pj = pair_j(p);
    const unsigned short* Xp = XT + (size_t)pi * DIM * PITCH;
    const unsigned short* Yp = XT + (size_t)pj * DIM * PITCH;

    int tid = threadIdx.x;
    int w = tid >> 6;                // wave 0..7 -> k-slice within each chunk
    int L = tid & 63;

    // Staging map: 32 rows x 256 shorts per matrix = 1024 x 16B pieces; 512
    // threads take 2 pieces each (rows 0-15 pass0, 16-31 pass1). Row reads are
    // fully contiguous 512 B segments.
    int srow = tid >> 5;             // 0..15
    int soff = (tid & 31) * 8;       // short offset 0..248
    const unsigned short* gA0 = Xp + (size_t)(a0 + srow) * PITCH + soff;
    const unsigned short* gA1 = Xp + (size_t)(a0 + 16 + srow) * PITCH + soff;
    const unsigned short* gB0 = Yp + (size_t)(b0 + srow) * PITCH + soff;
    const unsigned short* gB1 = Yp + (size_t)(b0 + 16 + srow) * PITCH + soff;
    int lA0 = srow * APITCH + soff;
    int lA1 = (16 + srow) * APITCH + soff;

    // prefetch chunk 0
    bf16x8 ra0 = *(const bf16x8*)gA0;
    bf16x8 ra1 = *(const bf16x8*)gA1;
    bf16x8 rb0 = *(const bf16x8*)gB0;
    bf16x8 rb1 = *(const bf16x8*)gB1;

    f32x4 acc[2][2] = {};
    int koff = w * 32 + (L >> 4) * 8;    // short offset of this wave's k-slice
    int frA0 = (L & 15) * APITCH + koff;
    int frA1 = (16 + (L & 15)) * APITCH + koff;

    for (int c = 0; c < 16; ++c) {
        __syncthreads();                 // previous chunk fully consumed
        *(bf16x8*)&As[lA0] = ra0;
        *(bf16x8*)&As[lA1] = ra1;
        *(bf16x8*)&Bs[lA0] = rb0;
        *(bf16x8*)&Bs[lA1] = rb1;
        int cn = (c < 15) ? (c + 1) * BK : 0;   // clamp: harmless re-read on last
        ra0 = *(const bf16x8*)(gA0 + cn);
        ra1 = *(const bf16x8*)(gA1 + cn);
        rb0 = *(const bf16x8*)(gB0 + cn);
        rb1 = *(const bf16x8*)(gB1 + cn);
        __syncthreads();                 // stage ready
        bf16x8 a0f = *(const bf16x8*)&As[frA0];
        bf16x8 a1f = *(const bf16x8*)&As[frA1];
        bf16x8 b0f = *(const bf16x8*)&Bs[frA0];
        bf16x8 b1f = *(const bf16x8*)&Bs[frA1];
        acc[0][0] = __builtin_amdgcn_mfma_f32_16x16x32_bf16(a0f, b0f, acc[0][0], 0, 0, 0);
        acc[0][1] = __builtin_amdgcn_mfma_f32_16x16x32_bf16(a0f, b1f, acc[0][1], 0, 0, 0);
        acc[1][0] = __builtin_amdgcn_mfma_f32_16x16x32_bf16(a1f, b0f, acc[1][0], 0, 0, 0);
        acc[1][1] = __builtin_amdgcn_mfma_f32_16x16x32_bf16(a1f, b1f, acc[1][1], 0, 0, 0);
    }

    __syncthreads();                     // all frag reads done; smem becomes red

    // C/D layout: col = lane&15, row = (lane>>4)*4 + reg   [measured m89/m91]
    #pragma unroll
    for (int ti = 0; ti < 2; ++ti)
        #pragma unroll
        for (int tj = 0; tj < 2; ++tj)
            #pragma unroll
            for (int r = 0; r < 4; ++r) {
                int m = ti * 16 + (L >> 4) * 4 + r;
                int n = tj * 16 + (L & 15);
                red[w * 1056 + m * 33 + n] = acc[ti][tj][r];
            }
    __syncthreads();

    const float inv_b = 1.0f / (float)B_ROWS;
    float local = 0.f;
    #pragma unroll
    for (int q = 0; q < 2; ++q) {
        int pos = tid + q * 512;
        int m = pos >> 5, n = pos & 31;
        float s = 0.f;
        #pragma unroll
        for (int ww = 0; ww < 8; ++ww) s += red[ww * 1056 + m * 33 + n];
        float v = s - sums[pi * DIM + a0 + m] * sums[pj * DIM + b0 + n] * inv_b;
        local = fmaf(v, v, local);
    }
    #pragma unroll
    for (int off = 32; off > 0; off >>= 1) local += __shfl_down(local, off, 64);
    __shared__ float wsum[8];
    if (L == 0) wsum[w] = local;
    __syncthreads();
    if (tid == 0) {
        float s = 0.f;
        #pragma unroll
        for (int ww = 0; ww < 8; ++ww) s += wsum[ww];
        atomicAdd(acc_out, s);
    }
}

// Kernel 3: scale and write the scalar output (float32)
__global__ void finalize_kernel(const float* __restrict__ acc, float* __restrict__ out) {
    if (threadIdx.x == 0) {
        const float scale = 0.1f / (6.0f * 4095.0f * 4095.0f);
        out[0] = acc[0] * scale;
    }
}

// ============================ FALLBACK (R3 passing fp32 path) ============================

__global__ void col_sums_kernel(const float* __restrict__ e0, const float* __restrict__ e1,
                                const float* __restrict__ e2, const float* __restrict__ e3,
                                float* __restrict__ sums) {
    int e = blockIdx.y;
    const float* X = sel(e0, e1, e2, e3, e);
    int c = threadIdx.x;
    int r0 = blockIdx.x * 128;
    float s = 0.f;
    #pragma unroll 4
    for (int r = r0; r < r0 + 128; ++r) s += X[r * DIM + c];
    atomicAdd(&sums[e * DIM + c], s);
}

__global__ __launch_bounds__(256) void gram_kernel(
        const float* __restrict__ e0, const float* __restrict__ e1,
        const float* __restrict__ e2, const float* __restrict__ e3,
        float* __restrict__ G) {
    int kc = blockIdx.x;
    int tile = blockIdx.y;
    int p = blockIdx.z;
    const float* X = sel(e0, e1, e2, e3, pair_i(p));
    const float* Y = sel(e0, e1, e2, e3, pair_j(p));
    int a0 = (tile >> 2) * 64;
    int b0 = (tile & 3) * 64;
    int k0 = kc * KCHUNK;
    __shared__ float As[16][64];
    __shared__ float Bs[16][64];
    int lid = threadIdx.x;
    int lr = lid >> 4;
    int lc = (lid & 15) << 2;
    int ty = lid >> 4;
    int tx = lid & 15;
    float acc[4][4] = {};
    for (int ks = 0; ks < KCHUNK; ks += 16) {
        int row = k0 + ks + lr;
        float4 av = *(const float4*)&X[row * DIM + a0 + lc];
        float4 bv = *(const float4*)&Y[row * DIM + b0 + lc];
        __syncthreads();
        *(float4*)&As[lr][lc] = av;
        *(float4*)&Bs[lr][lc] = bv;
        __syncthreads();
        #pragma unroll
        for (int k = 0; k < 16; ++k) {
            float a[4], b[4];
            *(float4*)a = *(const float4*)&As[k][ty * 4];
            *(float4*)b = *(const float4*)&Bs[k][tx * 4];
            #pragma unroll
            for (int i = 0; i < 4; ++i)
                #pragma unroll
                for (int j = 0; j < 4; ++j)
                    acc[i][j] = fmaf(a[i], b[j], acc[i][j]);
        }
    }
    float* Gp = G + p * (DIM * DIM);
    #pragma unroll
    for (int i = 0; i < 4; ++i)
        #pragma unroll
        for (int j = 0; j < 4; ++j)
            atomicAdd(&Gp[(a0 + ty * 4 + i) * DIM + (b0 + tx * 4 + j)], acc[i][j]);
}

__global__ void reduce_kernel(const float* __restrict__ G, const float* __restrict__ sums,
                              float* __restrict__ acc) {
    float local = 0.f;
    const int total = NPAIR * DIM * DIM;
    for (int idx = blockIdx.x * blockDim.x + threadIdx.x; idx < total;
         idx += gridDim.x * blockDim.x) {
        int p = idx >> 16;
        int ab = idx & 65535;
        int a = ab >> 8;
        int b = ab & 255;
        float v = G[idx] - sums[pair_i(p) * DIM + a] * sums[pair_j(p) * DIM + b] * (1.0f / (float)B_ROWS);
        local = fmaf(v, v, local);
    }
    #pragma unroll
    for (int off = 32; off > 0; off >>= 1) local += __shfl_down(local, off, 64);
    __shared__ float wsum[4];
    if ((threadIdx.x & 63) == 0) wsum[threadIdx.x >> 6] = local;
    __syncthreads();
    if (threadIdx.x == 0) {
        float s = wsum[0] + wsum[1] + wsum[2] + wsum[3];
        atomicAdd(acc, s);
    }
}

// ============================ LAUNCH ============================

extern "C" void kernel_launch(void* const* d_in, const int* in_sizes, int n_in,
                              void* d_out, int out_size, void* d_ws, size_t ws_size,
                              hipStream_t stream) {
    const float* e0 = (const float*)d_in[0];
    const float* e1 = (const float*)d_in[1];
    const float* e2 = (const float*)d_in[2];
    const float* e3 = (const float*)d_in[3];

    float* sums = (float*)d_ws;                            // 4*256 f32 = 4 KB
    float* acc  = (float*)((char*)d_ws + 4096);            // 1 f32
    size_t need = 8192 + (size_t)4 * DIM * PITCH * sizeof(unsigned short);

    if (ws_size >= need) {
        unsigned short* XT = (unsigned short*)((char*)d_ws + 8192);
        hipMemsetAsync(d_ws, 0, 8192, stream);   // sums + acc
        transpose_bf16_kernel<<<dim3(64, 4, 4), 256, 0, stream>>>(e0, e1, e2, e3, XT, sums);
        gram_v3_kernel<<<NPAIR * 64, 512, 0, stream>>>(XT, sums, acc);
        finalize_kernel<<<1, 64, 0, stream>>>(acc, (float*)d_out);
    } else {
        // fallback: fp32 vector path (passed in R3)
        float* G = (float*)((char*)d_ws + 8192);
        size_t zbytes = 8192 + (size_t)NPAIR * DIM * DIM * sizeof(float);
        hipMemsetAsync(d_ws, 0, zbytes, stream);
        col_sums_kernel<<<dim3(32, 4), 256, 0, stream>>>(e0, e1, e2, e3, sums);
        gram_kernel<<<dim3(KSPLIT, 16, NPAIR), 256, 0, stream>>>(e0, e1, e2, e3, G);
        reduce_kernel<<<384, 256, 0, stream>>>(G, sums, acc);
        finalize_kernel<<<1, 64, 0, stream>>>(acc, (float*)d_out);
    }
}